// Round 1
// baseline (1914.439 us; speedup 1.0000x reference)
//
#include <hip/hip_runtime.h>
#include <math.h>

#define H 512
#define V 32000
#define NVB 125     // vocab blocks (32000 / 256)
#define NT 256      // vocab tile width
#define MT 64       // row tile height
#define BK 16       // K chunk

// ---------------------------------------------------------------------------
// Kernel 1: ts = tanh(A @ W_em + b_em), A = [y_hidden (2048x512); y_null (1x512)]
// 64x64 tile per WG, 256 threads, 4x4 per thread.
// ---------------------------------------------------------------------------
__global__ __launch_bounds__(256) void k_emstate(
    const float* __restrict__ y_hidden,   // 2048x512
    const float* __restrict__ y_null,     // 1x512
    const float* __restrict__ W,          // 512x512 row-major
    const float* __restrict__ bias,       // 512
    float* __restrict__ ts)               // 2049x512
{
    const int NR = 2049;
    __shared__ float As[BK][64];   // transposed: [k][row]
    __shared__ float Bs[BK][64];   // [k][col]
    int rb = blockIdx.y, cb = blockIdx.x;
    int row0 = rb * 64, col0 = cb * 64;
    int tid = threadIdx.x;
    int tr = tid >> 4, tc = tid & 15;
    float acc[4][4] = {};
    for (int k0 = 0; k0 < H; k0 += BK) {
        {
            int r = tid >> 2;
            int kk = (tid & 3) << 2;
            int row = row0 + r;
            float4 v = make_float4(0.f, 0.f, 0.f, 0.f);
            if (row < 2048)       v = *(const float4*)&y_hidden[row * H + k0 + kk];
            else if (row == 2048) v = *(const float4*)&y_null[k0 + kk];
            As[kk + 0][r] = v.x; As[kk + 1][r] = v.y;
            As[kk + 2][r] = v.z; As[kk + 3][r] = v.w;
            int bk = tid >> 4, bc = (tid & 15) << 2;
            *(float4*)&Bs[bk][bc] = *(const float4*)&W[(k0 + bk) * H + col0 + bc];
        }
        __syncthreads();
#pragma unroll
        for (int kk = 0; kk < BK; ++kk) {
            float4 a = *(float4*)&As[kk][tr * 4];
            float4 b = *(float4*)&Bs[kk][tc * 4];
            float av[4] = {a.x, a.y, a.z, a.w};
            float bv[4] = {b.x, b.y, b.z, b.w};
#pragma unroll
            for (int i = 0; i < 4; i++)
#pragma unroll
                for (int j = 0; j < 4; j++) acc[i][j] += av[i] * bv[j];
        }
        __syncthreads();
    }
#pragma unroll
    for (int i = 0; i < 4; i++) {
        int row = row0 + tr * 4 + i;
        if (row >= NR) break;
#pragma unroll
        for (int j = 0; j < 4; j++) {
            int col = col0 + tc * 4 + j;
            ts[row * H + col] = tanhf(acc[i][j] + bias[col]);
        }
    }
}

// ---------------------------------------------------------------------------
// Kernel 2: fused logits GEMM + per-(row, vocab-block) softmax partials.
// C_tile = A(64xK) @ W(KxNT) + bias. Per row of the tile: block max, block
// sum(exp(x-max)), block argmax (first occurrence). 8x8 per thread.
// ---------------------------------------------------------------------------
__global__ __launch_bounds__(256) void k_logits_partial(
    const float* __restrict__ A,     // nrows x 512
    const float* __restrict__ W,     // 512 x 32000 row-major
    const float* __restrict__ bias,  // 32000
    int nrows,
    float* __restrict__ pM, float* __restrict__ pL, int* __restrict__ pI)
{
    __shared__ float As[BK][MT];   // [k][row]
    __shared__ float Bs[BK][NT];   // [k][col]
    int vb = blockIdx.x, rb = blockIdx.y;
    int row0 = rb * MT, col0 = vb * NT;
    int tid = threadIdx.x;
    int tr = tid >> 5, tc = tid & 31;
    float acc[8][8] = {};
    for (int k0 = 0; k0 < H; k0 += BK) {
        {
            // A tile: 64 rows x 16 k, transposed into As
            int r = tid >> 2;
            int kk = (tid & 3) << 2;
            int row = row0 + r;
            float4 v = make_float4(0.f, 0.f, 0.f, 0.f);
            if (row < nrows) v = *(const float4*)&A[row * H + k0 + kk];
            As[kk + 0][r] = v.x; As[kk + 1][r] = v.y;
            As[kk + 2][r] = v.z; As[kk + 3][r] = v.w;
            // B tile: 16 k x 256 cols; fully coalesced float4 loads
#pragma unroll
            for (int p = 0; p < 4; ++p) {
                int q = tid + 256 * p;           // float4 id in [0,1024)
                int bk = q >> 6;                 // k within chunk
                int bc = (q & 63) << 2;          // col within tile
                *(float4*)&Bs[bk][bc] =
                    *(const float4*)&W[(k0 + bk) * V + col0 + bc];
            }
        }
        __syncthreads();
#pragma unroll
        for (int kk = 0; kk < BK; ++kk) {
            float4 a0 = *(float4*)&As[kk][tr * 8];
            float4 a1 = *(float4*)&As[kk][tr * 8 + 4];
            float4 b0 = *(float4*)&Bs[kk][tc * 8];
            float4 b1 = *(float4*)&Bs[kk][tc * 8 + 4];
            float av[8] = {a0.x, a0.y, a0.z, a0.w, a1.x, a1.y, a1.z, a1.w};
            float bv[8] = {b0.x, b0.y, b0.z, b0.w, b1.x, b1.y, b1.z, b1.w};
#pragma unroll
            for (int i = 0; i < 8; i++)
#pragma unroll
                for (int j = 0; j < 8; j++) acc[i][j] += av[i] * bv[j];
        }
        __syncthreads();
    }
    // add bias
    float bv[8];
    *(float4*)&bv[0] = *(const float4*)&bias[col0 + tc * 8];
    *(float4*)&bv[4] = *(const float4*)&bias[col0 + tc * 8 + 4];
    // per-row reductions across the 32 threads (one aligned half-wave) of a row group
#pragma unroll
    for (int i = 0; i < 8; i++) {
        float lmax = -1e30f; int lidx = 0x7fffffff;
#pragma unroll
        for (int j = 0; j < 8; j++) {
            float v = acc[i][j] + bv[j];
            acc[i][j] = v;
            if (v > lmax) { lmax = v; lidx = col0 + tc * 8 + j; }
        }
        for (int m = 1; m < 32; m <<= 1) {
            float om = __shfl_xor(lmax, m, 64);
            int   oi = __shfl_xor(lidx, m, 64);
            if (om > lmax || (om == lmax && oi < lidx)) { lmax = om; lidx = oi; }
        }
        float lsum = 0.f;
#pragma unroll
        for (int j = 0; j < 8; j++) lsum += __expf(acc[i][j] - lmax);
        for (int m = 1; m < 32; m <<= 1) lsum += __shfl_xor(lsum, m, 64);
        if (tc == 0) {
            int row = row0 + tr * 8 + i;
            if (row < nrows) {
                pM[row * NVB + vb] = lmax;
                pL[row * NVB + vb] = lsum;
                pI[row * NVB + vb] = lidx;
            }
        }
    }
}

// ---------------------------------------------------------------------------
// Kernel 3: combine 125 partials per row -> global max M, denom L, argmax.
// One wave per row.
// ---------------------------------------------------------------------------
__global__ __launch_bounds__(256) void k_combine(
    const float* __restrict__ pM, const float* __restrict__ pL,
    const int* __restrict__ pI, int nrows,
    float* __restrict__ M, float* __restrict__ L, int* __restrict__ AI)
{
    int w = threadIdx.x >> 6;
    int ll = threadIdx.x & 63;
    int row = blockIdx.x * 4 + w;
    if (row >= nrows) return;
    const float* m = &pM[row * NVB];
    const float* l = &pL[row * NVB];
    const int*  ii = &pI[row * NVB];
    float bm = -1e30f; int bi = 0x7fffffff;
    for (int vb = ll; vb < NVB; vb += 64) {
        float v = m[vb]; int idx = ii[vb];
        if (v > bm || (v == bm && idx < bi)) { bm = v; bi = idx; }
    }
    for (int s = 1; s < 64; s <<= 1) {
        float om = __shfl_xor(bm, s, 64); int oi = __shfl_xor(bi, s, 64);
        if (om > bm || (om == bm && oi < bi)) { bm = om; bi = oi; }
    }
    float sum = 0.f;
    for (int vb = ll; vb < NVB; vb += 64) sum += l[vb] * __expf(m[vb] - bm);
    for (int s = 1; s < 64; s <<= 1) sum += __shfl_xor(sum, s, 64);
    if (ll == 0) { M[row] = bm; L[row] = sum; if (AI) AI[row] = bi; }
}

// ---------------------------------------------------------------------------
// Kernel 4: emission output. One WG per (b, tx). Stage W_sv[:, sources[b,tx]]
// in LDS; 65 dot products (64 ty rows + null row), write probs.
// out[b][y][x], y<64: em_g; y>=64: null broadcast over ty.
// ---------------------------------------------------------------------------
__global__ __launch_bounds__(256) void k_emission(
    const float* __restrict__ ts,     // 2049x512 (row 2048 = null)
    const float* __restrict__ W_sv,   // 512x32000
    const float* __restrict__ b_sv,
    const int* __restrict__ sources,  // 32x64
    const float* __restrict__ M, const float* __restrict__ L,
    float* __restrict__ out)          // 32x128x64
{
    __shared__ float wcol[H];
    __shared__ float sbias;
    int b = blockIdx.y, tx = blockIdx.x;
    int tid = threadIdx.x;
    int s = sources[b * 64 + tx];
    wcol[tid]       = W_sv[tid * V + s];
    wcol[tid + 256] = W_sv[(tid + 256) * V + s];
    if (tid == 0) sbias = b_sv[s];
    __syncthreads();
    int w = tid >> 6, ll = tid & 63;
    for (int r = w; r <= 64; r += 4) {
        int row = (r < 64) ? (b * 64 + r) : 2048;
        const float* a = &ts[row * H];
        float sum = 0.f;
#pragma unroll
        for (int j = 0; j < 8; ++j) sum += a[ll * 8 + j] * wcol[ll * 8 + j];
        for (int m2 = 1; m2 < 64; m2 <<= 1) sum += __shfl_xor(sum, m2, 64);
        float prob = __expf(sum + sbias - M[row]) / L[row];
        if (r < 64) {
            if (ll == 0) out[b * 8192 + r * 64 + tx] = prob;
        } else {
            out[b * 8192 + (64 + ll) * 64 + tx] = prob;  // null row, all ty
        }
    }
}

// ---------------------------------------------------------------------------
// Kernel 5: target-side epilogue. One wave per (b,t) row.
// ---------------------------------------------------------------------------
__global__ __launch_bounds__(256) void k_target(
    const float* __restrict__ tstate,  // 2048x512
    const float* __restrict__ W_tv, const float* __restrict__ b_tv,
    const int* __restrict__ targets,   // 2048
    const int* __restrict__ tlen,      // 32
    const float* __restrict__ M, const float* __restrict__ L,
    const int* __restrict__ AI,
    float* __restrict__ out_exp, float* __restrict__ out_log,
    float* __restrict__ out_pred)
{
    int w = threadIdx.x >> 6, ll = threadIdx.x & 63;
    int row = blockIdx.x * 4 + w;
    if (row >= 2048) return;
    int bb = row >> 6, t = row & 63;
    int tok = targets[row];
    const float* a = &tstate[row * H];
    float sum = 0.f;
#pragma unroll
    for (int j = 0; j < 8; ++j) {
        int k = ll * 8 + j;
        sum += a[k] * W_tv[k * V + tok];
    }
    for (int m2 = 1; m2 < 64; m2 <<= 1) sum += __shfl_xor(sum, m2, 64);
    if (ll == 0) {
        float logit = sum + b_tv[tok];
        float Mi = M[row], Li = L[row];
        float prob = __expf(logit - Mi) / Li;
        int mask = (t < tlen[bb]) ? 1 : 0;
        out_exp[row]  = mask ? prob : 0.f;
        out_log[row]  = mask ? (logit - Mi - __logf(Li)) : 0.f;
        out_pred[row] = (float)AI[row];
    }
}

// ---------------------------------------------------------------------------
extern "C" void kernel_launch(void* const* d_in, const int* in_sizes, int n_in,
                              void* d_out, int out_size, void* d_ws, size_t ws_size,
                              hipStream_t stream)
{
    const float* y_hidden = (const float*)d_in[0];   // 32x64x512
    const float* y_null   = (const float*)d_in[1];   // 1x512
    const float* tstate   = (const float*)d_in[2];   // 32x64x512
    const float* W_em     = (const float*)d_in[3];   // 512x512
    const float* b_em     = (const float*)d_in[4];   // 512
    const float* W_sv     = (const float*)d_in[5];   // 512x32000
    const float* b_sv     = (const float*)d_in[6];   // 32000
    const float* W_tv     = (const float*)d_in[7];   // 512x32000
    const float* b_tv     = (const float*)d_in[8];   // 32000
    const int*   sources  = (const int*)d_in[9];     // 32x64
    const int*   targets  = (const int*)d_in[10];    // 32x64
    const int*   tlen     = (const int*)d_in[11];    // 32

    float* out = (float*)d_out;
    float* out_em   = out;             // 262144
    float* out_exp  = out + 262144;    // 2048
    float* out_log  = out + 264192;    // 2048
    float* out_pred = out + 266240;    // 2048

    // workspace layout (floats)
    float* ws = (float*)d_ws;
    const size_t NR0 = 2049, NR1 = 2048;
    float* ts   = ws;                        size_t off = NR0 * H;        // 2049x512
    float* pM0  = ws + off; off += NR0 * NVB;
    float* pL0  = ws + off; off += NR0 * NVB;
    int*   pI0  = (int*)(ws + off); off += NR0 * NVB;
    float* pM1  = ws + off; off += NR1 * NVB;
    float* pL1  = ws + off; off += NR1 * NVB;
    int*   pI1  = (int*)(ws + off); off += NR1 * NVB;
    float* M0   = ws + off; off += NR0;
    float* L0   = ws + off; off += NR0;
    float* M1   = ws + off; off += NR1;
    float* L1   = ws + off; off += NR1;
    int*   AI1  = (int*)(ws + off); off += NR1;

    // 1) ts = tanh([y_hidden; y_null] @ W_em + b_em)
    k_emstate<<<dim3(8, 33), 256, 0, stream>>>(y_hidden, y_null, W_em, b_em, ts);

    // 2) fused logits GEMM + softmax partials, both sides
    k_logits_partial<<<dim3(NVB, 33), 256, 0, stream>>>(ts, W_sv, b_sv, (int)NR0,
                                                        pM0, pL0, pI0);
    k_logits_partial<<<dim3(NVB, 32), 256, 0, stream>>>(tstate, W_tv, b_tv, (int)NR1,
                                                        pM1, pL1, pI1);

    // 3) combine partials
    k_combine<<<(2049 + 3) / 4, 256, 0, stream>>>(pM0, pL0, pI0, (int)NR0, M0, L0, nullptr);
    k_combine<<<2048 / 4, 256, 0, stream>>>(pM1, pL1, pI1, (int)NR1, M1, L1, AI1);

    // 4) emission gather
    k_emission<<<dim3(64, 32), 256, 0, stream>>>(ts, W_sv, b_sv, sources, M0, L0, out_em);

    // 5) target epilogue
    k_target<<<2048 / 4, 256, 0, stream>>>(tstate, W_tv, b_tv, targets, tlen,
                                           M1, L1, AI1, out_exp, out_log, out_pred);
}